// Round 10
// baseline (300.854 us; speedup 1.0000x reference)
//
#include <hip/hip_runtime.h>

#define B_  4
#define C_  16
#define H_  256
#define W_  256
#define CO_ 16
#define KS_ 3
#define KK_ 9
#define HW_ (H_ * W_)
// ws layout (u32 words): [0, IMG_WORDS) bf16 NHWC image, then kbuf B-frags
#define IMG_WORDS ((size_t)B_ * HW_ * 8)   // 32 B per pixel
#define KER_OFF   IMG_WORDS
#define NKB 5                               // k-blocks: K=160 (144 + 16 pad)

typedef __attribute__((ext_vector_type(8))) short bf16x8;
typedef __attribute__((ext_vector_type(4))) float f32x4;
union U4S8 { uint4 u; bf16x8 s; };

#define LOBF(u) __uint_as_float((u) << 16)
#define HIBF(u) __uint_as_float((u) & 0xffff0000u)

__device__ __forceinline__ unsigned rne_bf16(float v) {
    unsigned b = __float_as_uint(v);
    return (b + 0x7fffu + ((b >> 16) & 1u)) >> 16;
}

// ------- Kernel 1: NCHW fp32 -> NHWC bf16 pack + B-fragment kernel pack ----
__global__ __launch_bounds__(256) void pack_nhwc_bf16(
    const float* __restrict__ inp, const float* __restrict__ ker,
    unsigned* __restrict__ wsu)
{
    const int t = threadIdx.x;
    const int e = blockIdx.x * 256 + t;     // flat pixel (b*HW + hw)
    const int b = e >> 16;
    const int hw = e & (HW_ - 1);
    const float* src = inp + (size_t)b * (C_ * HW_) + hw;
    float v[C_];
#pragma unroll
    for (int c = 0; c < C_; c++)
        v[c] = src[c * HW_];                // coalesced per c-plane
    unsigned u[8];
#pragma unroll
    for (int j = 0; j < 8; j++)
        u[j] = rne_bf16(v[2 * j]) | (rne_bf16(v[2 * j + 1]) << 16);
    uint4* dst = ((uint4*)wsu) + (size_t)e * 2;   // 32 B per pixel
    dst[0] = make_uint4(u[0], u[1], u[2], u[3]);
    dst[1] = make_uint4(u[4], u[5], u[6], u[7]);

    if (blockIdx.x == 0) {
        // kbuf: B-fragment layout for mfma_f32_16x16x32_bf16.
        // word i = (blk*64 + lane)*4 + wj holds bf16 pair (j=2wj, 2wj+1):
        //   B[k][n]: k = (lane>>4)*8 + j, n = o = lane&15,
        //   tap = 2*blk + (k>>4), c = k&15; zero when tap > 8 (K padding).
        for (int i = t; i < NKB * 256; i += 256) {
            const int wj  = i & 3;
            const int l   = (i >> 2) & 63;
            const int blk = i >> 8;
            const int o   = l & 15;
            unsigned lo = 0, hi = 0;
            {
                int j = 2 * wj, k = (l >> 4) * 8 + j;
                int tap = 2 * blk + (k >> 4), c = k & 15;
                if (tap <= 8) lo = rne_bf16(ker[(o * C_ + c) * KK_ + tap]);
                j = 2 * wj + 1; k = (l >> 4) * 8 + j;
                tap = 2 * blk + (k >> 4); c = k & 15;
                if (tap <= 8) hi = rne_bf16(ker[(o * C_ + c) * KK_ + tap]);
            }
            wsu[KER_OFF + i] = lo | (hi << 16);
        }
    }
}

// ------- tap address/weight setup ------------------------------------------
__device__ __forceinline__ void tap_setup(
    int h, int w, int kk, float dy, float dx,
    int* idx, float* wt)
{
    const float y = dy + (float)(h - 1 + kk / KS_);
    const float x = dx + (float)(w - 1 + kk % KS_);
    const float y0f = floorf(y);
    const float x0f = floorf(x);
    const int   y0  = (int)y0f;
    const int   x0  = (int)x0f;
    const float wy  = y - y0f;
    const float wx  = x - x0f;

    float w00 = (1.f - wy) * (1.f - wx);
    float w01 = (1.f - wy) * wx;
    float w10 = wy * (1.f - wx);
    float w11 = wy * wx;

    const bool v0y = ((unsigned)y0       < (unsigned)H_);
    const bool v1y = ((unsigned)(y0 + 1) < (unsigned)H_);
    const bool v0x = ((unsigned)x0       < (unsigned)W_);
    const bool v1x = ((unsigned)(x0 + 1) < (unsigned)W_);

    wt[0] = (v0y & v0x) ? w00 : 0.f;
    wt[1] = (v0y & v1x) ? w01 : 0.f;
    wt[2] = (v1y & v0x) ? w10 : 0.f;
    wt[3] = (v1y & v1x) ? w11 : 0.f;

    const int y0c = min(max(y0,     0), H_ - 1);
    const int y1c = min(max(y0 + 1, 0), H_ - 1);
    const int x0c = min(max(x0,     0), W_ - 1);
    const int x1c = min(max(x0 + 1, 0), W_ - 1);

    idx[0] = y0c * W_ + x0c;
    idx[1] = y0c * W_ + x1c;
    idx[2] = y1c * W_ + x0c;
    idx[3] = y1c * W_ + x1c;
}

__device__ __forceinline__ unsigned blendpack(
    unsigned a, unsigned b, unsigned c, unsigned d,
    float w0, float w1, float w2, float w3)
{
    const float lo = w0 * LOBF(a) + w1 * LOBF(b) + w2 * LOBF(c) + w3 * LOBF(d);
    const float hi = w0 * HIBF(a) + w1 * HIBF(b) + w2 * HIBF(c) + w3 * HIBF(d);
    return rne_bf16(lo) | (rne_bf16(hi) << 16);
}

// ------- Kernel 2: deform-conv + MSE via MFMA ------------------------------
// Wave = 16 pixels (A rows m) x 4 k-quads. Lane(q=l>>4, m=l&15) holds
// k = q*8+j = (tap, 8 channels) -> one 16B half of a bf16 NHWC record.
// acc[p][o] accumulated by 5 chained mfma_f32_16x16x32_bf16.
__global__ __launch_bounds__(256) void deform_loss_mfma(
    const float* __restrict__ off, const unsigned* __restrict__ wsu,
    const float* __restrict__ tgt, float* __restrict__ out)
{
    // XCD swizzle: bijection on [0,4096); xcd = blk&7 covers 512 consecutive
    // 64-pixel groups = 128 contiguous rows -> per-XCD L2 locality
    const int f = (blockIdx.x & 7) * 512 + (blockIdx.x >> 3);
    const int t = threadIdx.x;
    const int l = t & 63;
    const int q = l >> 4;
    const int m = l & 15;
    const int base = f * 64 + (t >> 6) * 16;     // wave's 16-pixel base
    const int pix  = base + m;
    const int b    = pix >> 16;
    const int hw   = pix & (HW_ - 1);
    const int h    = hw >> 8;
    const int w    = hw & (W_ - 1);

    const float* offb = off + (size_t)b * (2 * KK_ * HW_) + hw;
    const uint4* ib   = ((const uint4*)wsu) + (size_t)b * HW_ * 2;
    const uint4* kb   = (const uint4*)(wsu + KER_OFF);

    // B-fragments (kernel weights): 5 x 16 B, register-resident all kernel
    bf16x8 bfr[NKB];
#pragma unroll
    for (int kbk = 0; kbk < NKB; kbk++) {
        U4S8 cv; cv.u = kb[kbk * 64 + l];
        bfr[kbk] = cv.s;
    }

    // this lane's (dy,dx) per k-block — all 10 loads issued at entry.
    // tap>8 clamped to 8: reads valid memory; contribution zeroed by B=0.
    float dyv[NKB], dxv[NKB];
#pragma unroll
    for (int kbk = 0; kbk < NKB; kbk++) {
        const int tap = min(2 * kbk + (q >> 1), KK_ - 1);
        dyv[kbk] = offb[(2 * tap) * HW_];
        dxv[kbk] = offb[(2 * tap + 1) * HW_];
    }

    f32x4 acc = {0.f, 0.f, 0.f, 0.f};
    uint4 cor[2][4];
    float wts[2][4];

    // prologue: k-block 0 gathers (4 x 16 B, lane's channel-half of corners)
    {
        int idx[4];
        tap_setup(h, w, min(q >> 1, KK_ - 1), dyv[0], dxv[0], idx, wts[0]);
#pragma unroll
        for (int i = 0; i < 4; i++) cor[0][i] = ib[idx[i] * 2 + (q & 1)];
    }

#pragma unroll
    for (int kbk = 0; kbk < NKB; kbk++) {
        const int cur = kbk & 1, nxt = cur ^ 1;
        if (kbk + 1 < NKB) {
            int idx[4];
            tap_setup(h, w, min(2 * (kbk + 1) + (q >> 1), KK_ - 1),
                      dyv[kbk + 1], dxv[kbk + 1], idx, wts[nxt]);
#pragma unroll
            for (int i = 0; i < 4; i++) cor[nxt][i] = ib[idx[i] * 2 + (q & 1)];
        }

        const float w0 = wts[cur][0], w1 = wts[cur][1],
                    w2 = wts[cur][2], w3 = wts[cur][3];
        const uint4 c0 = cor[cur][0], c1 = cor[cur][1],
                    c2 = cor[cur][2], c3 = cor[cur][3];
        uint4 A4;
        A4.x = blendpack(c0.x, c1.x, c2.x, c3.x, w0, w1, w2, w3);
        A4.y = blendpack(c0.y, c1.y, c2.y, c3.y, w0, w1, w2, w3);
        A4.z = blendpack(c0.z, c1.z, c2.z, c3.z, w0, w1, w2, w3);
        A4.w = blendpack(c0.w, c1.w, c2.w, c3.w, w0, w1, w2, w3);
        U4S8 ca; ca.u = A4;

        acc = __builtin_amdgcn_mfma_f32_16x16x32_bf16(ca.s, bfr[kbk], acc, 0, 0, 0);
    }

    // C/D layout: col = lane&15 = o, row = 4*(lane>>4)+reg = pixel-in-group
    const int o   = m;
    const int hwb = (base & (HW_ - 1)) + 4 * q;
    const float4 tv = *(const float4*)(tgt + (size_t)b * (CO_ * HW_)
                                       + (size_t)o * HW_ + hwb);
    float d0 = acc[0] - tv.x, d1 = acc[1] - tv.y,
          d2 = acc[2] - tv.z, d3 = acc[3] - tv.w;
    float part = (d0 * d0 + d1 * d1 + d2 * d2 + d3 * d3)
               * (1.0f / (float)((size_t)B_ * CO_ * HW_));

#pragma unroll
    for (int sft = 32; sft > 0; sft >>= 1)
        part += __shfl_down(part, sft, 64);
    if (l == 0)
        atomicAdd(out, part);
}

// ------- Fallback (round-1 NCHW kernel, used if ws too small) --------------
__global__ __launch_bounds__(256) void deform_loss_kernel(
    const float* __restrict__ off, const float* __restrict__ inp,
    const float* __restrict__ ker, const float* __restrict__ tgt,
    float* __restrict__ out)
{
    const int idx = blockIdx.x * blockDim.x + threadIdx.x;
    float part = 0.f;
    if (idx < B_ * H_ * W_) {
        const int w  = idx & (W_ - 1);
        const int h  = (idx >> 8) & (H_ - 1);
        const int b  = idx >> 16;
        const int hw = h * W_ + w;
        const float* offb = off + (size_t)b * (2 * KK_ * HW_);
        const float* inpb = inp + (size_t)b * (C_ * HW_);
        float acc[CO_];
#pragma unroll
        for (int o = 0; o < CO_; o++) acc[o] = 0.f;
        for (int kk = 0; kk < KK_; kk++) {
            const float dy = offb[(2 * kk)     * HW_ + hw];
            const float dx = offb[(2 * kk + 1) * HW_ + hw];
            const float y = dy + (float)(h - 1 + kk / KS_);
            const float x = dx + (float)(w - 1 + kk % KS_);
            const float y0f = floorf(y);
            const float x0f = floorf(x);
            const int   y0  = (int)y0f;
            const int   x0  = (int)x0f;
            const float wy  = y - y0f;
            const float wx  = x - x0f;
            float w00 = (1.f - wy) * (1.f - wx);
            float w01 = (1.f - wy) * wx;
            float w10 = wy * (1.f - wx);
            float w11 = wy * wx;
            const bool v0y = ((unsigned)y0       < (unsigned)H_);
            const bool v1y = ((unsigned)(y0 + 1) < (unsigned)H_);
            const bool v0x = ((unsigned)x0       < (unsigned)W_);
            const bool v1x = ((unsigned)(x0 + 1) < (unsigned)W_);
            w00 = (v0y & v0x) ? w00 : 0.f;
            w01 = (v0y & v1x) ? w01 : 0.f;
            w10 = (v1y & v0x) ? w10 : 0.f;
            w11 = (v1y & v1x) ? w11 : 0.f;
            const int i00 = min(max(y0,0),H_-1)*W_ + min(max(x0,0),W_-1);
            const int i01 = min(max(y0,0),H_-1)*W_ + min(max(x0+1,0),W_-1);
            const int i10 = min(max(y0+1,0),H_-1)*W_ + min(max(x0,0),W_-1);
            const int i11 = min(max(y0+1,0),H_-1)*W_ + min(max(x0+1,0),W_-1);
            for (int c = 0; c < C_; c++) {
                const float* pp = inpb + c * HW_;
                const float s = pp[i00]*w00 + pp[i01]*w01 + pp[i10]*w10 + pp[i11]*w11;
#pragma unroll
                for (int o = 0; o < CO_; o++)
                    acc[o] = fmaf(s, ker[(o * C_ + c) * KK_ + kk], acc[o]);
            }
        }
        const float* tb = tgt + (size_t)b * (CO_ * HW_);
#pragma unroll
        for (int o = 0; o < CO_; o++) {
            const float d = acc[o] - tb[o * HW_ + hw];
            part = fmaf(d, d, part);
        }
        part *= (1.0f / (float)((size_t)B_ * CO_ * HW_));
    }
#pragma unroll
    for (int sft = 32; sft > 0; sft >>= 1)
        part += __shfl_down(part, sft, 64);
    if ((threadIdx.x & 63) == 0)
        atomicAdd(out, part);
}

extern "C" void kernel_launch(void* const* d_in, const int* in_sizes, int n_in,
                              void* d_out, int out_size, void* d_ws, size_t ws_size,
                              hipStream_t stream) {
    const float* offsets = (const float*)d_in[0];
    const float* input   = (const float*)d_in[1];
    const float* ker     = (const float*)d_in[2];
    const float* target  = (const float*)d_in[3];
    float* out = (float*)d_out;

    hipMemsetAsync(out, 0, sizeof(float), stream);

    const size_t need = (KER_OFF + NKB * 256) * sizeof(unsigned);
    if (ws_size >= need) {
        unsigned* wsu = (unsigned*)d_ws;
        pack_nhwc_bf16<<<(B_ * HW_) / 256, 256, 0, stream>>>(input, ker, wsu);
        // 4096 blocks x 256 threads: wave = 16 pixels x 4 k-quads
        deform_loss_mfma<<<(B_ * HW_) / 64, 256, 0, stream>>>(offsets, wsu, target, out);
    } else {
        const int total = B_ * H_ * W_;
        deform_loss_kernel<<<(total + 255) / 256, 256, 0, stream>>>(
            offsets, input, ker, target, out);
    }
}

// Round 11
// 119.783 us; speedup vs baseline: 2.5117x; 2.5117x over previous
//
#include <hip/hip_runtime.h>

#define B_  4
#define C_  16
#define H_  256
#define W_  256
#define CO_ 16
#define KS_ 3
#define KK_ 9
#define HW_ (H_ * W_)
// ws layout (floats): [0, IMG_WORDS) bf16 NHWC image (as u32), t_ker, partials
#define IMG_WORDS ((size_t)B_ * HW_ * 8)        // 2,097,152 u32 words
#define KER_OFF   IMG_WORDS                     // float offset of t_ker
#define PART_OFF  (KER_OFF + (size_t)KK_ * C_ * CO_)  // per-block partials
#define NBLK 1024

#define LOBF(u) __uint_as_float((u) << 16)
#define HIBF(u) __uint_as_float((u) & 0xffff0000u)

__device__ __forceinline__ unsigned rne_bf16(float v) {
    unsigned b = __float_as_uint(v);
    return (b + 0x7fffu + ((b >> 16) & 1u)) >> 16;
}

// ------- Kernel 1: NCHW fp32 -> NHWC bf16 pack + ker transpose -------------
__global__ __launch_bounds__(256) void pack_nhwc_bf16(
    const float* __restrict__ inp, const float* __restrict__ ker,
    float* __restrict__ wsp)
{
    unsigned* wsu = (unsigned*)wsp;
    const int t = threadIdx.x;
    const int e = blockIdx.x * 256 + t;     // flat pixel (b*HW + hw)
    const int b = e >> 16;
    const int hw = e & (HW_ - 1);
    const float* src = inp + (size_t)b * (C_ * HW_) + hw;
    float v[C_];
#pragma unroll
    for (int c = 0; c < C_; c++)
        v[c] = src[c * HW_];                // coalesced per c-plane
    unsigned u[8];
#pragma unroll
    for (int j = 0; j < 8; j++)
        u[j] = rne_bf16(v[2 * j]) | (rne_bf16(v[2 * j + 1]) << 16);
    uint4* dst = ((uint4*)wsu) + (size_t)e * 2;   // 32 B per pixel
    dst[0] = make_uint4(u[0], u[1], u[2], u[3]);
    dst[1] = make_uint4(u[4], u[5], u[6], u[7]);

    if (blockIdx.x == 0) {
        // t_ker[kk*256 + c*16 + o] = ker[(o*16+c)*9 + kk]
        for (int i = t; i < KK_ * C_ * CO_; i += 256) {
            const int kk = i >> 8;
            const int c  = (i >> 4) & 15;
            const int o  = i & 15;
            wsp[KER_OFF + i] = ker[(o * C_ + c) * KK_ + kk];
        }
    }
}

// ------- tap address/weight setup (pure VALU once offsets are in regs) -----
__device__ __forceinline__ void tap_setup(
    int h, int w, int kk, float dy, float dx,
    int* idx, float* wt)
{
    const float y = dy + (float)(h - 1 + kk / KS_);
    const float x = dx + (float)(w - 1 + kk % KS_);
    const float y0f = floorf(y);
    const float x0f = floorf(x);
    const int   y0  = (int)y0f;
    const int   x0  = (int)x0f;
    const float wy  = y - y0f;
    const float wx  = x - x0f;

    float w00 = (1.f - wy) * (1.f - wx);
    float w01 = (1.f - wy) * wx;
    float w10 = wy * (1.f - wx);
    float w11 = wy * wx;

    const bool v0y = ((unsigned)y0       < (unsigned)H_);
    const bool v1y = ((unsigned)(y0 + 1) < (unsigned)H_);
    const bool v0x = ((unsigned)x0       < (unsigned)W_);
    const bool v1x = ((unsigned)(x0 + 1) < (unsigned)W_);

    wt[0] = (v0y & v0x) ? w00 : 0.f;
    wt[1] = (v0y & v1x) ? w01 : 0.f;
    wt[2] = (v1y & v0x) ? w10 : 0.f;
    wt[3] = (v1y & v1x) ? w11 : 0.f;

    const int y0c = min(max(y0,     0), H_ - 1);
    const int y1c = min(max(y0 + 1, 0), H_ - 1);
    const int x0c = min(max(x0,     0), W_ - 1);
    const int x1c = min(max(x0 + 1, 0), W_ - 1);

    idx[0] = y0c * W_ + x0c;
    idx[1] = y0c * W_ + x1c;
    idx[2] = y1c * W_ + x0c;
    idx[3] = y1c * W_ + x1c;
}

__device__ __forceinline__ void load8(
    uint4* cor, const uint4* __restrict__ ib, const int* idx)
{
    cor[0] = ib[idx[0] * 2]; cor[1] = ib[idx[0] * 2 + 1];
    cor[2] = ib[idx[1] * 2]; cor[3] = ib[idx[1] * 2 + 1];
    cor[4] = ib[idx[2] * 2]; cor[5] = ib[idx[2] * 2 + 1];
    cor[6] = ib[idx[3] * 2]; cor[7] = ib[idx[3] * 2 + 1];
}

__device__ __forceinline__ void blend2(
    unsigned a, unsigned b, unsigned c, unsigned d,
    float w0, float w1, float w2, float w3, float* s)
{
    s[0] = w0 * LOBF(a) + w1 * LOBF(b) + w2 * LOBF(c) + w3 * LOBF(d);
    s[1] = w0 * HIBF(a) + w1 * HIBF(b) + w2 * HIBF(c) + w3 * HIBF(d);
}

// ------- Kernel 2: deform-conv + MSE, block partial -> ws (NO atomics) -----
__global__ __launch_bounds__(256) void deform_loss_bf16(
    const float* __restrict__ off, const float* __restrict__ wsp,
    const float* __restrict__ tgt, float* __restrict__ partials)
{
    // XCD swizzle: bijection on [0,1024); xcd = blk&7 gets 128 contiguous
    // rows of one image -> per-XCD L2 locality (round-4 verified)
    const int bh = (blockIdx.x & 7) * 128 + (blockIdx.x >> 3);
    const int b  = bh >> 8;
    const int h  = bh & (H_ - 1);
    const int w  = threadIdx.x;
    const int hw = h * W_ + w;

    const float* offb = off + (size_t)b * (2 * KK_ * HW_) + hw;
    const uint4* ib   = ((const uint4*)wsp) + (size_t)b * HW_ * 2;
    const float* tker = wsp + KER_OFF;
    const float* tb   = tgt + (size_t)b * (CO_ * HW_) + hw;

    // ALL 18 offset loads issued at entry — in flight together, one latency
    float dyv[KK_], dxv[KK_];
#pragma unroll
    for (int kk = 0; kk < KK_; kk++) {
        dyv[kk] = offb[(2 * kk)     * HW_];
        dxv[kk] = offb[(2 * kk + 1) * HW_];
    }

    float acc[CO_];
#pragma unroll
    for (int o = 0; o < CO_; o++) acc[o] = 0.f;

    uint4 cor[2][8];
    float wts[2][4];
    float tv[CO_];

    // prologue: tap 0 setup + gathers
    {
        int idx[4];
        tap_setup(h, w, 0, dyv[0], dxv[0], idx, wts[0]);
        load8(cor[0], ib, idx);
    }

#pragma unroll
    for (int kk = 0; kk < KK_; kk++) {
        const int cur = kk & 1, nxt = cur ^ 1;

        // issue next tap's gathers first; in flight across blend + FMA block
        if (kk + 1 < KK_) {
            int idx[4];
            tap_setup(h, w, kk + 1, dyv[kk + 1], dxv[kk + 1], idx, wts[nxt]);
            load8(cor[nxt], ib, idx);
        } else {
#pragma unroll
            for (int o = 0; o < CO_; o++) tv[o] = tb[o * HW_];
        }

        // consume: unpack bf16 + bilinear blend -> sc[16]
        const uint4* cc = cor[cur];
        const float w0 = wts[cur][0], w1 = wts[cur][1],
                    w2 = wts[cur][2], w3 = wts[cur][3];
        float sc[C_];
        blend2(cc[0].x, cc[2].x, cc[4].x, cc[6].x, w0, w1, w2, w3, sc + 0);
        blend2(cc[0].y, cc[2].y, cc[4].y, cc[6].y, w0, w1, w2, w3, sc + 2);
        blend2(cc[0].z, cc[2].z, cc[4].z, cc[6].z, w0, w1, w2, w3, sc + 4);
        blend2(cc[0].w, cc[2].w, cc[4].w, cc[6].w, w0, w1, w2, w3, sc + 6);
        blend2(cc[1].x, cc[3].x, cc[5].x, cc[7].x, w0, w1, w2, w3, sc + 8);
        blend2(cc[1].y, cc[3].y, cc[5].y, cc[7].y, w0, w1, w2, w3, sc + 10);
        blend2(cc[1].z, cc[3].z, cc[5].z, cc[7].z, w0, w1, w2, w3, sc + 12);
        blend2(cc[1].w, cc[3].w, cc[5].w, cc[7].w, w0, w1, w2, w3, sc + 14);

        // accumulate: kt is wave-uniform -> s_load broadcasts, FMA w/ SGPR
        const float* kt = tker + kk * (C_ * CO_);
#pragma unroll
        for (int c = 0; c < C_; c++) {
            const float s = sc[c];
#pragma unroll
            for (int o = 0; o < CO_; o++)
                acc[o] = fmaf(s, kt[c * 16 + o], acc[o]);
        }
    }

    float part = 0.f;
#pragma unroll
    for (int o = 0; o < CO_; o++) {
        const float d = acc[o] - tv[o];
        part = fmaf(d, d, part);
    }
    part *= (1.0f / (float)((size_t)B_ * CO_ * HW_));

    // wave reduce -> LDS -> ONE plain store per block (no atomics)
#pragma unroll
    for (int sft = 32; sft > 0; sft >>= 1)
        part += __shfl_down(part, sft, 64);

    __shared__ float red[4];
    if ((threadIdx.x & 63) == 0)
        red[threadIdx.x >> 6] = part;
    __syncthreads();
    if (threadIdx.x == 0)
        partials[blockIdx.x] = red[0] + red[1] + red[2] + red[3];
}

// ------- Kernel 3: sum 1024 block partials -> out --------------------------
__global__ __launch_bounds__(256) void reduce_partials(
    const float* __restrict__ partials, float* __restrict__ out)
{
    const int t = threadIdx.x;
    float s = partials[t] + partials[t + 256]
            + partials[t + 512] + partials[t + 768];
#pragma unroll
    for (int sft = 32; sft > 0; sft >>= 1)
        s += __shfl_down(s, sft, 64);
    __shared__ float red[4];
    if ((t & 63) == 0) red[t >> 6] = s;
    __syncthreads();
    if (t == 0) out[0] = red[0] + red[1] + red[2] + red[3];
}

// ------- Fallback (round-1 NCHW kernel, used if ws too small) --------------
__global__ __launch_bounds__(256) void deform_loss_kernel(
    const float* __restrict__ off, const float* __restrict__ inp,
    const float* __restrict__ ker, const float* __restrict__ tgt,
    float* __restrict__ out)
{
    const int idx = blockIdx.x * blockDim.x + threadIdx.x;
    float part = 0.f;
    if (idx < B_ * H_ * W_) {
        const int w  = idx & (W_ - 1);
        const int h  = (idx >> 8) & (H_ - 1);
        const int b  = idx >> 16;
        const int hw = h * W_ + w;
        const float* offb = off + (size_t)b * (2 * KK_ * HW_);
        const float* inpb = inp + (size_t)b * (C_ * HW_);
        float acc[CO_];
#pragma unroll
        for (int o = 0; o < CO_; o++) acc[o] = 0.f;
        for (int kk = 0; kk < KK_; kk++) {
            const float dy = offb[(2 * kk)     * HW_ + hw];
            const float dx = offb[(2 * kk + 1) * HW_ + hw];
            const float y = dy + (float)(h - 1 + kk / KS_);
            const float x = dx + (float)(w - 1 + kk % KS_);
            const float y0f = floorf(y);
            const float x0f = floorf(x);
            const int   y0  = (int)y0f;
            const int   x0  = (int)x0f;
            const float wy  = y - y0f;
            const float wx  = x - x0f;
            float w00 = (1.f - wy) * (1.f - wx);
            float w01 = (1.f - wy) * wx;
            float w10 = wy * (1.f - wx);
            float w11 = wy * wx;
            const bool v0y = ((unsigned)y0       < (unsigned)H_);
            const bool v1y = ((unsigned)(y0 + 1) < (unsigned)H_);
            const bool v0x = ((unsigned)x0       < (unsigned)W_);
            const bool v1x = ((unsigned)(x0 + 1) < (unsigned)W_);
            w00 = (v0y & v0x) ? w00 : 0.f;
            w01 = (v0y & v1x) ? w01 : 0.f;
            w10 = (v1y & v0x) ? w10 : 0.f;
            w11 = (v1y & v1x) ? w11 : 0.f;
            const int i00 = min(max(y0,0),H_-1)*W_ + min(max(x0,0),W_-1);
            const int i01 = min(max(y0,0),H_-1)*W_ + min(max(x0+1,0),W_-1);
            const int i10 = min(max(y0+1,0),H_-1)*W_ + min(max(x0,0),W_-1);
            const int i11 = min(max(y0+1,0),H_-1)*W_ + min(max(x0+1,0),W_-1);
            for (int c = 0; c < C_; c++) {
                const float* pp = inpb + c * HW_;
                const float s = pp[i00]*w00 + pp[i01]*w01 + pp[i10]*w10 + pp[i11]*w11;
#pragma unroll
                for (int o = 0; o < CO_; o++)
                    acc[o] = fmaf(s, ker[(o * C_ + c) * KK_ + kk], acc[o]);
            }
        }
        const float* tb = tgt + (size_t)b * (CO_ * HW_);
#pragma unroll
        for (int o = 0; o < CO_; o++) {
            const float d = acc[o] - tb[o * HW_ + hw];
            part = fmaf(d, d, part);
        }
        part *= (1.0f / (float)((size_t)B_ * CO_ * HW_));
    }
#pragma unroll
    for (int sft = 32; sft > 0; sft >>= 1)
        part += __shfl_down(part, sft, 64);
    if ((threadIdx.x & 63) == 0)
        atomicAdd(out, part);
}

extern "C" void kernel_launch(void* const* d_in, const int* in_sizes, int n_in,
                              void* d_out, int out_size, void* d_ws, size_t ws_size,
                              hipStream_t stream) {
    const float* offsets = (const float*)d_in[0];
    const float* input   = (const float*)d_in[1];
    const float* ker     = (const float*)d_in[2];
    const float* target  = (const float*)d_in[3];
    float* out = (float*)d_out;

    const size_t need = (PART_OFF + NBLK) * sizeof(float);
    if (ws_size >= need) {
        float* wsp = (float*)d_ws;
        pack_nhwc_bf16<<<(B_ * HW_) / 256, 256, 0, stream>>>(input, ker, wsp);
        deform_loss_bf16<<<NBLK, 256, 0, stream>>>(offsets, wsp, target,
                                                   wsp + PART_OFF);
        reduce_partials<<<1, 256, 0, stream>>>(wsp + PART_OFF, out);
    } else {
        hipMemsetAsync(out, 0, sizeof(float), stream);
        const int total = B_ * H_ * W_;
        deform_loss_kernel<<<(total + 255) / 256, 256, 0, stream>>>(
            offsets, input, ker, target, out);
    }
}

// Round 12
// 115.666 us; speedup vs baseline: 2.6011x; 1.0356x over previous
//
#include <hip/hip_runtime.h>

#define B_  4
#define C_  16
#define H_  256
#define W_  256
#define CO_ 16
#define KS_ 3
#define KK_ 9
#define HW_ (H_ * W_)
// ws layout (u32 words): bf16 NHWC image | kbuf B-frags | partials (float)
#define IMG_WORDS ((size_t)B_ * HW_ * 8)   // 32 B per pixel
#define KER_OFF   IMG_WORDS
#define NKB 5                               // k-blocks: K=160 (144 + 16 pad)
#define NBLK 4096
#define PART_OFF (KER_OFF + (size_t)NKB * 256)

typedef __attribute__((ext_vector_type(8))) short bf16x8;
typedef __attribute__((ext_vector_type(4))) float f32x4;
union U4S8 { uint4 u; bf16x8 s; };

#define LOBF(u) __uint_as_float((u) << 16)
#define HIBF(u) __uint_as_float((u) & 0xffff0000u)

__device__ __forceinline__ unsigned rne_bf16(float v) {
    unsigned b = __float_as_uint(v);
    return (b + 0x7fffu + ((b >> 16) & 1u)) >> 16;
}

// ------- Kernel 1: NCHW fp32 -> NHWC bf16 pack + B-fragment kernel pack ----
__global__ __launch_bounds__(256) void pack_nhwc_bf16(
    const float* __restrict__ inp, const float* __restrict__ ker,
    unsigned* __restrict__ wsu)
{
    const int t = threadIdx.x;
    const int e = blockIdx.x * 256 + t;     // flat pixel (b*HW + hw)
    const int b = e >> 16;
    const int hw = e & (HW_ - 1);
    const float* src = inp + (size_t)b * (C_ * HW_) + hw;
    float v[C_];
#pragma unroll
    for (int c = 0; c < C_; c++)
        v[c] = src[c * HW_];                // coalesced per c-plane
    unsigned u[8];
#pragma unroll
    for (int j = 0; j < 8; j++)
        u[j] = rne_bf16(v[2 * j]) | (rne_bf16(v[2 * j + 1]) << 16);
    uint4* dst = ((uint4*)wsu) + (size_t)e * 2;   // 32 B per pixel
    dst[0] = make_uint4(u[0], u[1], u[2], u[3]);
    dst[1] = make_uint4(u[4], u[5], u[6], u[7]);

    if (blockIdx.x == 0) {
        // kbuf: B-fragment layout for mfma_f32_16x16x32_bf16.
        // word i = (blk*64 + lane)*4 + wj holds bf16 pair (j=2wj, 2wj+1):
        //   B[k][n]: k = (lane>>4)*8 + j, n = o = lane&15,
        //   tap = 2*blk + (k>>4), c = k&15; zero when tap > 8 (K padding).
        for (int i = t; i < NKB * 256; i += 256) {
            const int wj  = i & 3;
            const int l   = (i >> 2) & 63;
            const int blk = i >> 8;
            const int o   = l & 15;
            unsigned lo = 0, hi = 0;
            {
                int j = 2 * wj, k = (l >> 4) * 8 + j;
                int tap = 2 * blk + (k >> 4), c = k & 15;
                if (tap <= 8) lo = rne_bf16(ker[(o * C_ + c) * KK_ + tap]);
                j = 2 * wj + 1; k = (l >> 4) * 8 + j;
                tap = 2 * blk + (k >> 4); c = k & 15;
                if (tap <= 8) hi = rne_bf16(ker[(o * C_ + c) * KK_ + tap]);
            }
            wsu[KER_OFF + i] = lo | (hi << 16);
        }
    }
}

// ------- tap address/weight setup ------------------------------------------
__device__ __forceinline__ void tap_setup(
    int h, int w, int kk, float dy, float dx,
    int* idx, float* wt)
{
    const float y = dy + (float)(h - 1 + kk / KS_);
    const float x = dx + (float)(w - 1 + kk % KS_);
    const float y0f = floorf(y);
    const float x0f = floorf(x);
    const int   y0  = (int)y0f;
    const int   x0  = (int)x0f;
    const float wy  = y - y0f;
    const float wx  = x - x0f;

    float w00 = (1.f - wy) * (1.f - wx);
    float w01 = (1.f - wy) * wx;
    float w10 = wy * (1.f - wx);
    float w11 = wy * wx;

    const bool v0y = ((unsigned)y0       < (unsigned)H_);
    const bool v1y = ((unsigned)(y0 + 1) < (unsigned)H_);
    const bool v0x = ((unsigned)x0       < (unsigned)W_);
    const bool v1x = ((unsigned)(x0 + 1) < (unsigned)W_);

    wt[0] = (v0y & v0x) ? w00 : 0.f;
    wt[1] = (v0y & v1x) ? w01 : 0.f;
    wt[2] = (v1y & v0x) ? w10 : 0.f;
    wt[3] = (v1y & v1x) ? w11 : 0.f;

    const int y0c = min(max(y0,     0), H_ - 1);
    const int y1c = min(max(y0 + 1, 0), H_ - 1);
    const int x0c = min(max(x0,     0), W_ - 1);
    const int x1c = min(max(x0 + 1, 0), W_ - 1);

    idx[0] = y0c * W_ + x0c;
    idx[1] = y0c * W_ + x1c;
    idx[2] = y1c * W_ + x0c;
    idx[3] = y1c * W_ + x1c;
}

__device__ __forceinline__ unsigned blendpack(
    unsigned a, unsigned b, unsigned c, unsigned d,
    float w0, float w1, float w2, float w3)
{
    const float lo = w0 * LOBF(a) + w1 * LOBF(b) + w2 * LOBF(c) + w3 * LOBF(d);
    const float hi = w0 * HIBF(a) + w1 * HIBF(b) + w2 * HIBF(c) + w3 * HIBF(d);
    return rne_bf16(lo) | (rne_bf16(hi) << 16);
}

// ------- Kernel 2: deform-conv + MSE via MFMA, NO atomics ------------------
// Wave = 16 pixels (A rows m) x 4 k-quads. Lane(q=l>>4, m=l&15) holds
// k = q*8+j = (tap, 8 channels) -> one 16B half of a bf16 NHWC record.
// acc[p][o] accumulated by 5 chained mfma_f32_16x16x32_bf16.
__global__ __launch_bounds__(256) void deform_loss_mfma(
    const float* __restrict__ off, const unsigned* __restrict__ wsu,
    const float* __restrict__ tgt, float* __restrict__ partials)
{
    // XCD swizzle: bijection on [0,4096); xcd = blk&7 covers 512 consecutive
    // 64-pixel groups = 128 contiguous rows -> per-XCD L2 locality
    const int f = (blockIdx.x & 7) * 512 + (blockIdx.x >> 3);
    const int t = threadIdx.x;
    const int l = t & 63;
    const int q = l >> 4;
    const int m = l & 15;
    const int base = f * 64 + (t >> 6) * 16;     // wave's 16-pixel base
    const int pix  = base + m;
    const int b    = pix >> 16;
    const int hw   = pix & (HW_ - 1);
    const int h    = hw >> 8;
    const int w    = hw & (W_ - 1);

    const float* offb = off + (size_t)b * (2 * KK_ * HW_) + hw;
    const uint4* ib   = ((const uint4*)wsu) + (size_t)b * HW_ * 2;
    const uint4* kb   = (const uint4*)(wsu + KER_OFF);

    // B-fragments (kernel weights): 5 x 16 B, register-resident all kernel
    bf16x8 bfr[NKB];
#pragma unroll
    for (int kbk = 0; kbk < NKB; kbk++) {
        U4S8 cv; cv.u = kb[kbk * 64 + l];
        bfr[kbk] = cv.s;
    }

    // this lane's (dy,dx) per k-block — all 10 loads issued at entry.
    // tap>8 clamped to 8: reads valid memory; contribution zeroed by B=0.
    float dyv[NKB], dxv[NKB];
#pragma unroll
    for (int kbk = 0; kbk < NKB; kbk++) {
        const int tap = min(2 * kbk + (q >> 1), KK_ - 1);
        dyv[kbk] = offb[(2 * tap) * HW_];
        dxv[kbk] = offb[(2 * tap + 1) * HW_];
    }

    f32x4 acc = {0.f, 0.f, 0.f, 0.f};
    uint4 cor[2][4];
    float wts[2][4];

    // prologue: k-block 0 gathers (4 x 16 B, lane's channel-half of corners)
    {
        int idx[4];
        tap_setup(h, w, min(q >> 1, KK_ - 1), dyv[0], dxv[0], idx, wts[0]);
#pragma unroll
        for (int i = 0; i < 4; i++) cor[0][i] = ib[idx[i] * 2 + (q & 1)];
    }

#pragma unroll
    for (int kbk = 0; kbk < NKB; kbk++) {
        const int cur = kbk & 1, nxt = cur ^ 1;
        if (kbk + 1 < NKB) {
            int idx[4];
            tap_setup(h, w, min(2 * (kbk + 1) + (q >> 1), KK_ - 1),
                      dyv[kbk + 1], dxv[kbk + 1], idx, wts[nxt]);
#pragma unroll
            for (int i = 0; i < 4; i++) cor[nxt][i] = ib[idx[i] * 2 + (q & 1)];
        }

        const float w0 = wts[cur][0], w1 = wts[cur][1],
                    w2 = wts[cur][2], w3 = wts[cur][3];
        const uint4 c0 = cor[cur][0], c1 = cor[cur][1],
                    c2 = cor[cur][2], c3 = cor[cur][3];
        uint4 A4;
        A4.x = blendpack(c0.x, c1.x, c2.x, c3.x, w0, w1, w2, w3);
        A4.y = blendpack(c0.y, c1.y, c2.y, c3.y, w0, w1, w2, w3);
        A4.z = blendpack(c0.z, c1.z, c2.z, c3.z, w0, w1, w2, w3);
        A4.w = blendpack(c0.w, c1.w, c2.w, c3.w, w0, w1, w2, w3);
        U4S8 ca; ca.u = A4;

        acc = __builtin_amdgcn_mfma_f32_16x16x32_bf16(ca.s, bfr[kbk], acc, 0, 0, 0);
    }

    // C/D layout: col = lane&15 = o, row = 4*(lane>>4)+reg = pixel-in-group
    const int o   = m;
    const int hwb = (base & (HW_ - 1)) + 4 * q;
    const float4 tv = *(const float4*)(tgt + (size_t)b * (CO_ * HW_)
                                       + (size_t)o * HW_ + hwb);
    float d0 = acc[0] - tv.x, d1 = acc[1] - tv.y,
          d2 = acc[2] - tv.z, d3 = acc[3] - tv.w;
    float part = (d0 * d0 + d1 * d1 + d2 * d2 + d3 * d3)
               * (1.0f / (float)((size_t)B_ * CO_ * HW_));

    // wave reduce -> LDS -> ONE plain store per block (no atomics)
#pragma unroll
    for (int sft = 32; sft > 0; sft >>= 1)
        part += __shfl_down(part, sft, 64);

    __shared__ float red[4];
    if (l == 0)
        red[t >> 6] = part;
    __syncthreads();
    if (t == 0)
        partials[blockIdx.x] = red[0] + red[1] + red[2] + red[3];
}

// ------- Kernel 3: sum 4096 block partials -> out --------------------------
__global__ __launch_bounds__(256) void reduce_partials(
    const float* __restrict__ partials, float* __restrict__ out)
{
    const int t = threadIdx.x;
    float s = 0.f;
#pragma unroll
    for (int i = 0; i < NBLK / 256; i++)
        s += partials[t + i * 256];
#pragma unroll
    for (int sft = 32; sft > 0; sft >>= 1)
        s += __shfl_down(s, sft, 64);
    __shared__ float red[4];
    if ((t & 63) == 0) red[t >> 6] = s;
    __syncthreads();
    if (t == 0) out[0] = red[0] + red[1] + red[2] + red[3];
}

// ------- Fallback (round-1 NCHW kernel, used if ws too small) --------------
__global__ __launch_bounds__(256) void deform_loss_kernel(
    const float* __restrict__ off, const float* __restrict__ inp,
    const float* __restrict__ ker, const float* __restrict__ tgt,
    float* __restrict__ out)
{
    const int idx = blockIdx.x * blockDim.x + threadIdx.x;
    float part = 0.f;
    if (idx < B_ * H_ * W_) {
        const int w  = idx & (W_ - 1);
        const int h  = (idx >> 8) & (H_ - 1);
        const int b  = idx >> 16;
        const int hw = h * W_ + w;
        const float* offb = off + (size_t)b * (2 * KK_ * HW_);
        const float* inpb = inp + (size_t)b * (C_ * HW_);
        float acc[CO_];
#pragma unroll
        for (int o = 0; o < CO_; o++) acc[o] = 0.f;
        for (int kk = 0; kk < KK_; kk++) {
            const float dy = offb[(2 * kk)     * HW_ + hw];
            const float dx = offb[(2 * kk + 1) * HW_ + hw];
            const float y = dy + (float)(h - 1 + kk / KS_);
            const float x = dx + (float)(w - 1 + kk % KS_);
            const float y0f = floorf(y);
            const float x0f = floorf(x);
            const int   y0  = (int)y0f;
            const int   x0  = (int)x0f;
            const float wy  = y - y0f;
            const float wx  = x - x0f;
            float w00 = (1.f - wy) * (1.f - wx);
            float w01 = (1.f - wy) * wx;
            float w10 = wy * (1.f - wx);
            float w11 = wy * wx;
            const bool v0y = ((unsigned)y0       < (unsigned)H_);
            const bool v1y = ((unsigned)(y0 + 1) < (unsigned)H_);
            const bool v0x = ((unsigned)x0       < (unsigned)W_);
            const bool v1x = ((unsigned)(x0 + 1) < (unsigned)W_);
            w00 = (v0y & v0x) ? w00 : 0.f;
            w01 = (v0y & v1x) ? w01 : 0.f;
            w10 = (v1y & v0x) ? w10 : 0.f;
            w11 = (v1y & v1x) ? w11 : 0.f;
            const int i00 = min(max(y0,0),H_-1)*W_ + min(max(x0,0),W_-1);
            const int i01 = min(max(y0,0),H_-1)*W_ + min(max(x0+1,0),W_-1);
            const int i10 = min(max(y0+1,0),H_-1)*W_ + min(max(x0,0),W_-1);
            const int i11 = min(max(y0+1,0),H_-1)*W_ + min(max(x0+1,0),W_-1);
            for (int c = 0; c < C_; c++) {
                const float* pp = inpb + c * HW_;
                const float s = pp[i00]*w00 + pp[i01]*w01 + pp[i10]*w10 + pp[i11]*w11;
#pragma unroll
                for (int o = 0; o < CO_; o++)
                    acc[o] = fmaf(s, ker[(o * C_ + c) * KK_ + kk], acc[o]);
            }
        }
        const float* tb = tgt + (size_t)b * (CO_ * HW_);
#pragma unroll
        for (int o = 0; o < CO_; o++) {
            const float d = acc[o] - tb[o * HW_ + hw];
            part = fmaf(d, d, part);
        }
        part *= (1.0f / (float)((size_t)B_ * CO_ * HW_));
    }
#pragma unroll
    for (int sft = 32; sft > 0; sft >>= 1)
        part += __shfl_down(part, sft, 64);
    if ((threadIdx.x & 63) == 0)
        atomicAdd(out, part);
}

extern "C" void kernel_launch(void* const* d_in, const int* in_sizes, int n_in,
                              void* d_out, int out_size, void* d_ws, size_t ws_size,
                              hipStream_t stream) {
    const float* offsets = (const float*)d_in[0];
    const float* input   = (const float*)d_in[1];
    const float* ker     = (const float*)d_in[2];
    const float* target  = (const float*)d_in[3];
    float* out = (float*)d_out;

    const size_t need = (PART_OFF + NBLK) * sizeof(unsigned);
    if (ws_size >= need) {
        unsigned* wsu = (unsigned*)d_ws;
        pack_nhwc_bf16<<<(B_ * HW_) / 256, 256, 0, stream>>>(input, ker, wsu);
        // 4096 blocks x 256 threads: wave = 16 pixels x 4 k-quads
        deform_loss_mfma<<<NBLK, 256, 0, stream>>>(
            offsets, wsu, target, (float*)(wsu + PART_OFF));
        reduce_partials<<<1, 256, 0, stream>>>(
            (const float*)(wsu + PART_OFF), out);
    } else {
        hipMemsetAsync(out, 0, sizeof(float), stream);
        const int total = B_ * H_ * W_;
        deform_loss_kernel<<<(total + 255) / 256, 256, 0, stream>>>(
            offsets, input, ker, target, out);
    }
}

// Round 13
// 112.452 us; speedup vs baseline: 2.6754x; 1.0286x over previous
//
#include <hip/hip_runtime.h>

#define B_  4
#define C_  16
#define H_  256
#define W_  256
#define CO_ 16
#define KS_ 3
#define KK_ 9
#define HW_ (H_ * W_)
// ws layout (u32 words): bf16 NHWC image | kbuf B-frags | partials (float)
#define IMG_WORDS ((size_t)B_ * HW_ * 8)   // 32 B per pixel
#define KER_OFF   IMG_WORDS
#define NKB 5                               // k-blocks per group: K=160
#define NBLK 2048                           // blocks: 128 pixels each
#define PART_OFF (KER_OFF + (size_t)NKB * 256)

typedef __attribute__((ext_vector_type(8))) short bf16x8;
typedef __attribute__((ext_vector_type(4))) float f32x4;
union U4S8 { uint4 u; bf16x8 s; };

#define LOBF(u) __uint_as_float((u) << 16)
#define HIBF(u) __uint_as_float((u) & 0xffff0000u)

__device__ __forceinline__ unsigned rne_bf16(float v) {
    unsigned b = __float_as_uint(v);
    return (b + 0x7fffu + ((b >> 16) & 1u)) >> 16;
}

// ------- Kernel 1: NCHW fp32 -> NHWC bf16 pack + B-fragment kernel pack ----
__global__ __launch_bounds__(256) void pack_nhwc_bf16(
    const float* __restrict__ inp, const float* __restrict__ ker,
    unsigned* __restrict__ wsu)
{
    const int t = threadIdx.x;
    const int e = blockIdx.x * 256 + t;     // flat pixel (b*HW + hw)
    const int b = e >> 16;
    const int hw = e & (HW_ - 1);
    const float* src = inp + (size_t)b * (C_ * HW_) + hw;
    float v[C_];
#pragma unroll
    for (int c = 0; c < C_; c++)
        v[c] = src[c * HW_];                // coalesced per c-plane
    unsigned u[8];
#pragma unroll
    for (int j = 0; j < 8; j++)
        u[j] = rne_bf16(v[2 * j]) | (rne_bf16(v[2 * j + 1]) << 16);
    uint4* dst = ((uint4*)wsu) + (size_t)e * 2;   // 32 B per pixel
    dst[0] = make_uint4(u[0], u[1], u[2], u[3]);
    dst[1] = make_uint4(u[4], u[5], u[6], u[7]);

    if (blockIdx.x == 0) {
        // kbuf: B-fragment layout for mfma_f32_16x16x32_bf16.
        //   B[k][n]: k = (lane>>4)*8 + j, n = o = lane&15,
        //   tap = 2*blk + (k>>4), c = k&15; zero when tap > 8 (K padding).
        for (int i = t; i < NKB * 256; i += 256) {
            const int wj  = i & 3;
            const int l   = (i >> 2) & 63;
            const int blk = i >> 8;
            const int o   = l & 15;
            unsigned lo = 0, hi = 0;
            {
                int j = 2 * wj, k = (l >> 4) * 8 + j;
                int tap = 2 * blk + (k >> 4), c = k & 15;
                if (tap <= 8) lo = rne_bf16(ker[(o * C_ + c) * KK_ + tap]);
                j = 2 * wj + 1; k = (l >> 4) * 8 + j;
                tap = 2 * blk + (k >> 4); c = k & 15;
                if (tap <= 8) hi = rne_bf16(ker[(o * C_ + c) * KK_ + tap]);
            }
            wsu[KER_OFF + i] = lo | (hi << 16);
        }
    }
}

// ------- tap address/weight setup ------------------------------------------
__device__ __forceinline__ void tap_setup(
    int h, int w, int kk, float dy, float dx,
    int* idx, float* wt)
{
    const float y = dy + (float)(h - 1 + kk / KS_);
    const float x = dx + (float)(w - 1 + kk % KS_);
    const float y0f = floorf(y);
    const float x0f = floorf(x);
    const int   y0  = (int)y0f;
    const int   x0  = (int)x0f;
    const float wy  = y - y0f;
    const float wx  = x - x0f;

    float w00 = (1.f - wy) * (1.f - wx);
    float w01 = (1.f - wy) * wx;
    float w10 = wy * (1.f - wx);
    float w11 = wy * wx;

    const bool v0y = ((unsigned)y0       < (unsigned)H_);
    const bool v1y = ((unsigned)(y0 + 1) < (unsigned)H_);
    const bool v0x = ((unsigned)x0       < (unsigned)W_);
    const bool v1x = ((unsigned)(x0 + 1) < (unsigned)W_);

    wt[0] = (v0y & v0x) ? w00 : 0.f;
    wt[1] = (v0y & v1x) ? w01 : 0.f;
    wt[2] = (v1y & v0x) ? w10 : 0.f;
    wt[3] = (v1y & v1x) ? w11 : 0.f;

    const int y0c = min(max(y0,     0), H_ - 1);
    const int y1c = min(max(y0 + 1, 0), H_ - 1);
    const int x0c = min(max(x0,     0), W_ - 1);
    const int x1c = min(max(x0 + 1, 0), W_ - 1);

    idx[0] = y0c * W_ + x0c;
    idx[1] = y0c * W_ + x1c;
    idx[2] = y1c * W_ + x0c;
    idx[3] = y1c * W_ + x1c;
}

// blend + truncation-pack to bf16 pair: one v_perm_b32 instead of RNE math.
__device__ __forceinline__ unsigned blendpack(
    unsigned a, unsigned b, unsigned c, unsigned d,
    float w0, float w1, float w2, float w3)
{
    const float lo = w0 * LOBF(a) + w1 * LOBF(b) + w2 * LOBF(c) + w3 * LOBF(d);
    const float hi = w0 * HIBF(a) + w1 * HIBF(b) + w2 * HIBF(c) + w3 * HIBF(d);
    // result = [hi:31-16 | lo:31-16]  (bytes a3,a2,b3,b2)
    return __builtin_amdgcn_perm(__float_as_uint(hi), __float_as_uint(lo),
                                 0x07060302u);
}

// ------- Kernel 2: deform-conv + MSE via MFMA, 2 groups/wave, no atomics ---
// Wave = 2 groups x 16 pixels x 4 k-quads. Lane(q=l>>4, m=l&15) holds
// k = q*8+j -> one 16B half of a bf16 NHWC record. 5 MFMAs per group.
__global__ __launch_bounds__(256) void deform_loss_mfma(
    const float* __restrict__ off, const unsigned* __restrict__ wsu,
    const float* __restrict__ tgt, float* __restrict__ partials)
{
    // XCD swizzle: bijection on [0,2048); xcd = blk&7 covers 256 consecutive
    // 128-pixel blocks = 128 contiguous rows -> per-XCD L2 locality
    const int f = (blockIdx.x & 7) * 256 + (blockIdx.x >> 3);
    const int t = threadIdx.x;
    const int l = t & 63;
    const int q = l >> 4;
    const int m = l & 15;
    const int base = f * 128 + (t >> 6) * 32;   // wave's 32-pixel span
    const int b    = base >> 16;                // span never crosses b
    const int hwb  = base & (HW_ - 1);
    const int h    = hwb >> 8;                  // same row for both groups
    const int w0   = (hwb & (W_ - 1)) + m;      // group g pixel w = w0+16g

    const float* offp = off + (size_t)b * (2 * KK_ * HW_) + (size_t)h * W_;
    const uint4* ib   = ((const uint4*)wsu) + (size_t)b * HW_ * 2;
    const uint4* kb   = (const uint4*)(wsu + KER_OFF);

    // B-fragments: 5 x 16 B, register-resident
    bf16x8 bfr[NKB];
#pragma unroll
    for (int kbk = 0; kbk < NKB; kbk++) {
        U4S8 cv; cv.u = kb[kbk * 64 + l];
        bfr[kbk] = cv.s;
    }

    // ALL entry loads issued together: 20 offsets + 2 target float4s.
    // tap>8 clamped to 8: valid memory; contribution zeroed by B=0 padding.
    float dyv[2][NKB], dxv[2][NKB];
#pragma unroll
    for (int g = 0; g < 2; g++)
#pragma unroll
        for (int kbk = 0; kbk < NKB; kbk++) {
            const int tap = min(2 * kbk + (q >> 1), KK_ - 1);
            dyv[g][kbk] = offp[(size_t)(2 * tap) * HW_ + w0 + 16 * g];
            dxv[g][kbk] = offp[(size_t)(2 * tap + 1) * HW_ + w0 + 16 * g];
        }
    // targets (C/D layout: col=lane&15=o, row=4q+reg=pixel-in-group)
    const float* tbase = tgt + (size_t)b * (CO_ * HW_) + (size_t)m * HW_
                       + hwb + 4 * q;
    const float4 tv0 = *(const float4*)(tbase);
    const float4 tv1 = *(const float4*)(tbase + 16);

    f32x4 acc[2] = {{0.f, 0.f, 0.f, 0.f}, {0.f, 0.f, 0.f, 0.f}};
    uint4 cor[2][4];
    float wts[2][4];

    // prologue: group 0, k-block 0
    {
        int idx[4];
        tap_setup(h, w0, min(q >> 1, KK_ - 1), dyv[0][0], dxv[0][0], idx, wts[0]);
#pragma unroll
        for (int i = 0; i < 4; i++) cor[0][i] = ib[idx[i] * 2 + (q & 1)];
    }

#pragma unroll
    for (int kbi = 0; kbi < 2 * NKB; kbi++) {
        const int cur = kbi & 1, nxt = cur ^ 1;
        if (kbi + 1 < 2 * NKB) {
            const int gn = (kbi + 1) / NKB, kn = (kbi + 1) % NKB;
            int idx[4];
            tap_setup(h, w0 + 16 * gn, min(2 * kn + (q >> 1), KK_ - 1),
                      dyv[gn][kn], dxv[gn][kn], idx, wts[nxt]);
#pragma unroll
            for (int i = 0; i < 4; i++) cor[nxt][i] = ib[idx[i] * 2 + (q & 1)];
        }

        const int g = kbi / NKB, kkb = kbi % NKB;
        const float w0_ = wts[cur][0], w1_ = wts[cur][1],
                    w2_ = wts[cur][2], w3_ = wts[cur][3];
        const uint4 c0 = cor[cur][0], c1 = cor[cur][1],
                    c2 = cor[cur][2], c3 = cor[cur][3];
        uint4 A4;
        A4.x = blendpack(c0.x, c1.x, c2.x, c3.x, w0_, w1_, w2_, w3_);
        A4.y = blendpack(c0.y, c1.y, c2.y, c3.y, w0_, w1_, w2_, w3_);
        A4.z = blendpack(c0.z, c1.z, c2.z, c3.z, w0_, w1_, w2_, w3_);
        A4.w = blendpack(c0.w, c1.w, c2.w, c3.w, w0_, w1_, w2_, w3_);
        U4S8 ca; ca.u = A4;

        acc[g] = __builtin_amdgcn_mfma_f32_16x16x32_bf16(ca.s, bfr[kkb],
                                                         acc[g], 0, 0, 0);
    }

    float d0 = acc[0][0] - tv0.x, d1 = acc[0][1] - tv0.y,
          d2 = acc[0][2] - tv0.z, d3 = acc[0][3] - tv0.w;
    float e0 = acc[1][0] - tv1.x, e1 = acc[1][1] - tv1.y,
          e2 = acc[1][2] - tv1.z, e3 = acc[1][3] - tv1.w;
    float part = (d0 * d0 + d1 * d1 + d2 * d2 + d3 * d3
                + e0 * e0 + e1 * e1 + e2 * e2 + e3 * e3)
               * (1.0f / (float)((size_t)B_ * CO_ * HW_));

    // wave reduce -> LDS -> ONE plain store per block (no atomics)
#pragma unroll
    for (int sft = 32; sft > 0; sft >>= 1)
        part += __shfl_down(part, sft, 64);

    __shared__ float red[4];
    if (l == 0)
        red[t >> 6] = part;
    __syncthreads();
    if (t == 0)
        partials[blockIdx.x] = red[0] + red[1] + red[2] + red[3];
}

// ------- Kernel 3: sum NBLK block partials -> out --------------------------
__global__ __launch_bounds__(256) void reduce_partials(
    const float* __restrict__ partials, float* __restrict__ out)
{
    const int t = threadIdx.x;
    float s = 0.f;
#pragma unroll
    for (int i = 0; i < NBLK / 256; i++)
        s += partials[t + i * 256];
#pragma unroll
    for (int sft = 32; sft > 0; sft >>= 1)
        s += __shfl_down(s, sft, 64);
    __shared__ float red[4];
    if ((t & 63) == 0) red[t >> 6] = s;
    __syncthreads();
    if (t == 0) out[0] = red[0] + red[1] + red[2] + red[3];
}

// ------- Fallback (round-1 NCHW kernel, used if ws too small) --------------
__global__ __launch_bounds__(256) void deform_loss_kernel(
    const float* __restrict__ off, const float* __restrict__ inp,
    const float* __restrict__ ker, const float* __restrict__ tgt,
    float* __restrict__ out)
{
    const int idx = blockIdx.x * blockDim.x + threadIdx.x;
    float part = 0.f;
    if (idx < B_ * H_ * W_) {
        const int w  = idx & (W_ - 1);
        const int h  = (idx >> 8) & (H_ - 1);
        const int b  = idx >> 16;
        const int hw = h * W_ + w;
        const float* offb = off + (size_t)b * (2 * KK_ * HW_);
        const float* inpb = inp + (size_t)b * (C_ * HW_);
        float acc[CO_];
#pragma unroll
        for (int o = 0; o < CO_; o++) acc[o] = 0.f;
        for (int kk = 0; kk < KK_; kk++) {
            const float dy = offb[(2 * kk)     * HW_ + hw];
            const float dx = offb[(2 * kk + 1) * HW_ + hw];
            const float y = dy + (float)(h - 1 + kk / KS_);
            const float x = dx + (float)(w - 1 + kk % KS_);
            const float y0f = floorf(y);
            const float x0f = floorf(x);
            const int   y0  = (int)y0f;
            const int   x0  = (int)x0f;
            const float wy  = y - y0f;
            const float wx  = x - x0f;
            float w00 = (1.f - wy) * (1.f - wx);
            float w01 = (1.f - wy) * wx;
            float w10 = wy * (1.f - wx);
            float w11 = wy * wx;
            const bool v0y = ((unsigned)y0       < (unsigned)H_);
            const bool v1y = ((unsigned)(y0 + 1) < (unsigned)H_);
            const bool v0x = ((unsigned)x0       < (unsigned)W_);
            const bool v1x = ((unsigned)(x0 + 1) < (unsigned)W_);
            w00 = (v0y & v0x) ? w00 : 0.f;
            w01 = (v0y & v1x) ? w01 : 0.f;
            w10 = (v1y & v0x) ? w10 : 0.f;
            w11 = (v1y & v1x) ? w11 : 0.f;
            const int i00 = min(max(y0,0),H_-1)*W_ + min(max(x0,0),W_-1);
            const int i01 = min(max(y0,0),H_-1)*W_ + min(max(x0+1,0),W_-1);
            const int i10 = min(max(y0+1,0),H_-1)*W_ + min(max(x0,0),W_-1);
            const int i11 = min(max(y0+1,0),H_-1)*W_ + min(max(x0+1,0),W_-1);
            for (int c = 0; c < C_; c++) {
                const float* pp = inpb + c * HW_;
                const float s = pp[i00]*w00 + pp[i01]*w01 + pp[i10]*w10 + pp[i11]*w11;
#pragma unroll
                for (int o = 0; o < CO_; o++)
                    acc[o] = fmaf(s, ker[(o * C_ + c) * KK_ + kk], acc[o]);
            }
        }
        const float* tb = tgt + (size_t)b * (CO_ * HW_);
#pragma unroll
        for (int o = 0; o < CO_; o++) {
            const float d = acc[o] - tb[o * HW_ + hw];
            part = fmaf(d, d, part);
        }
        part *= (1.0f / (float)((size_t)B_ * CO_ * HW_));
    }
#pragma unroll
    for (int sft = 32; sft > 0; sft >>= 1)
        part += __shfl_down(part, sft, 64);
    if ((threadIdx.x & 63) == 0)
        atomicAdd(out, part);
}

extern "C" void kernel_launch(void* const* d_in, const int* in_sizes, int n_in,
                              void* d_out, int out_size, void* d_ws, size_t ws_size,
                              hipStream_t stream) {
    const float* offsets = (const float*)d_in[0];
    const float* input   = (const float*)d_in[1];
    const float* ker     = (const float*)d_in[2];
    const float* target  = (const float*)d_in[3];
    float* out = (float*)d_out;

    const size_t need = (PART_OFF + NBLK) * sizeof(unsigned);
    if (ws_size >= need) {
        unsigned* wsu = (unsigned*)d_ws;
        pack_nhwc_bf16<<<(B_ * HW_) / 256, 256, 0, stream>>>(input, ker, wsu);
        // 2048 blocks x 256 threads: wave = 2 groups x 16 pixels x 4 k-quads
        deform_loss_mfma<<<NBLK, 256, 0, stream>>>(
            offsets, wsu, target, (float*)(wsu + PART_OFF));
        reduce_partials<<<1, 256, 0, stream>>>(
            (const float*)(wsu + PART_OFF), out);
    } else {
        hipMemsetAsync(out, 0, sizeof(float), stream);
        const int total = B_ * H_ * W_;
        deform_loss_kernel<<<(total + 255) / 256, 256, 0, stream>>>(
            offsets, input, ker, target, out);
    }
}